// Round 17
// baseline (291.548 us; speedup 1.0000x reference)
//
#include <hip/hip_runtime.h>

// SplineCNN on MI355X — fused gather+projection per layer (R16 gather geometry).
//
// Math order: s[n, k*CIN+c] = deginv * sum_{m in N(n)} basis_k(n,m) * h[m,c],
// root column appended; out = relu( [s | h] @ [w; root] + bias ), K=10*CIN, N=64.
// R16 (213.9us): barrier-free preprocess + lean gather (VGPR<=64, 8 blk/CU).
// THIS ROUND: drop the sp HBM round trip (84MB x2) + 3 GEMM launches by fusing
// the projection INTO the gather — WITHOUT touching the gather's geometry
// (R7's fusion failed by restructuring it: 16-row tiles, 41KB LDS, 20% occ).
// Phase 1 = R16 gather verbatim, s-row -> small LDS tile (5-10KB). One barrier.
// Phase 2: each wave computes 16 f-cols for ALL 4 rows: M=4 padded into one
// 16x16x32 MFMA M-tile (A-row = lr&3; D row g only uses A row g, so discarded
// rows are harmless duplicates), Wt streamed from L2 (<=160KB/blk, resident).
// LDS 15.4/20.6KB -> 8/7 blocks/CU: gather occupancy preserved.
// All tensors fp16 (fp32 accumulate); layer-2 fuses max-pool via atomicMax.

#define B_   32
#define N_   512
#define F_   64
#define CAP  128          // max neighbors per node (mean ~31; P(>128) ~ 18 sigma)

typedef float f32x4 __attribute__((ext_vector_type(4)));
typedef _Float16 f16x8 __attribute__((ext_vector_type(8)));
typedef _Float16 f16x2 __attribute__((ext_vector_type(2)));

// ---------------- preprocess: wave-per-row, barrier-free (R16-verbatim) ----------------
__global__ __launch_bounds__(512, 8) void preprocess_kernel(
    const float* __restrict__ adj, const float* __restrict__ coord,
    int* __restrict__ edge_m, float4* __restrict__ edge_w,
    int4* __restrict__ cnt4,
    float* __restrict__ deginv, unsigned int* __restrict__ gmax,
    const float* __restrict__ x, _Float16* __restrict__ hx,
    const float* __restrict__ w0, const float* __restrict__ root0,
    const float* __restrict__ w1, const float* __restrict__ root1,
    const float* __restrict__ w2, const float* __restrict__ root2,
    _Float16* __restrict__ wt0, _Float16* __restrict__ wt1,
    _Float16* __restrict__ wt2) {
  int tid = threadIdx.x, wave = tid >> 6, lane = tid & 63;
  if (tid == 0) gmax[blockIdx.x] = 0u;   // grid 2048 == B_*F_

  // ---- merged prep: idx space [0, R*32) convx; then packw for 3 layers ----
  {
    int idx = blockIdx.x * 512 + tid;    // covers 1,048,576 >= 688,128
    const int CX = B_ * N_ * 32;
    const int S0 = 64 * 1280, S1 = 64 * 640;
    if (idx < CX) {
      float4 v = ((const float4*)x)[idx];
      f16x2 p0, p1;
      p0[0] = (_Float16)v.x; p0[1] = (_Float16)v.y;
      p1[0] = (_Float16)v.z; p1[1] = (_Float16)v.w;
      uint2 u;
      u.x = __builtin_bit_cast(unsigned, p0);
      u.y = __builtin_bit_cast(unsigned, p1);
      ((uint2*)hx)[idx] = u;
    } else if (idx < CX + S0 + 2 * S1) {
      int r = idx - CX;
      const float *w, *root; _Float16* wt; int KP, CIN;
      if (r < S0)           { w = w0; root = root0; wt = wt0; KP = 1280; CIN = 128; }
      else if (r < S0 + S1) { w = w1; root = root1; wt = wt1; KP = 640;  CIN = 64;  r -= S0; }
      else                  { w = w2; root = root2; wt = wt2; KP = 640;  CIN = 64;  r -= S0 + S1; }
      int f = r / KP, k = r - f * KP;
      int ks = k / CIN, c = k - ks * CIN;
      float v = (ks < 9) ? w[((size_t)ks * CIN + c) * F_ + f]
                         : root[(size_t)c * F_ + f];
      wt[(size_t)f * KP + k] = (_Float16)v;
    }
  }

  int row = blockIdx.x * 8 + wave;       // one row per wave
  int b = row >> 9;
  float cxn = coord[(size_t)row * 2 + 0];
  float cyn = coord[(size_t)row * 2 + 1];

  // ---- pass 1: load + classify 8 chunks of 64; wave-uniform quad totals ----
  int   pq[8];                  // quad (0..3) or -1 if no edge
  float pfx[8], pfy[8];
  int q0 = 0, q1 = 0, q2 = 0, q3 = 0;
  #pragma unroll
  for (int c = 0; c < 8; ++c) {
    int m = c * 64 + lane;
    float a = adj[(size_t)row * N_ + m];
    bool flag = (a != 0.0f);
    float cxm = coord[(size_t)(b * N_ + m) * 2 + 0];
    float cym = coord[(size_t)(b * N_ + m) * 2 + 1];
    float vx = cxm - cxn + 1.0f;         // = u*2 (K-1 = 2, u in [0,1])
    float vy = cym - cyn + 1.0f;
    float i0x = fminf(fmaxf(floorf(vx), 0.0f), 1.0f);
    float i0y = fminf(fmaxf(floorf(vy), 0.0f), 1.0f);
    pfx[c] = vx - i0x;
    pfy[c] = vy - i0y;
    int quad = (int)i0x + 2 * (int)i0y;  // 0..3
    pq[c] = flag ? quad : -1;
    q0 += __popcll(__ballot(flag && quad == 0));
    q1 += __popcll(__ballot(flag && quad == 1));
    q2 += __popcll(__ballot(flag && quad == 2));
    q3 += __popcll(__ballot(flag && quad == 3));
  }
  int qt0 = q0, qt1 = q0 + q1, qt2 = qt1 + q2, qt3 = qt2 + q3;

  // ---- pass 2: running per-quad offsets -> quad-sorted edge writes ----
  int ro0 = 0, ro1 = qt0, ro2 = qt1, ro3 = qt2;   // quad base offsets
  #pragma unroll
  for (int c = 0; c < 8; ++c) {
    unsigned long long b0 = __ballot(pq[c] == 0);
    unsigned long long b1 = __ballot(pq[c] == 1);
    unsigned long long b2 = __ballot(pq[c] == 2);
    unsigned long long b3 = __ballot(pq[c] == 3);
    int q = pq[c];
    if (q >= 0) {
      unsigned long long myb = (q == 0) ? b0 : (q == 1) ? b1 : (q == 2) ? b2 : b3;
      int base = (q == 0) ? ro0 : (q == 1) ? ro1 : (q == 2) ? ro2 : ro3;
      int off = base + __popcll(myb & ((1ULL << lane) - 1ULL));
      if (off < CAP) {
        float fx = pfx[c], fy = pfy[c];
        float gx = 1.0f - fx, gy = 1.0f - fy;
        edge_m[(size_t)row * CAP + off] = c * 64 + lane;
        edge_w[(size_t)row * CAP + off] =
            make_float4(gx * gy, gx * fy, fx * gy, fx * fy);
      }
    }
    ro0 += __popcll(b0); ro1 += __popcll(b1);
    ro2 += __popcll(b2); ro3 += __popcll(b3);
  }
  if (lane == 0) {
    int C0 = min(qt0, CAP), C1 = min(qt1, CAP);
    int C2 = min(qt2, CAP), C3c = min(qt3, CAP);
    cnt4[row] = make_int4(C0, C1 - C0, C2 - C1, C3c - C2);
    deginv[row] = 1.0f / (float)(qt3 > 0 ? qt3 : 1);
  }
}

// ---------------- fused gather + projection ----------------
// 256 threads = 4 waves, ONE ROW PER WAVE (R16 gather geometry, unchanged);
// grid 4096, XCD-swizzled (batch b on XCD b>>2, h slice L2-resident).
// Phase 1: wave stages its edge list (m + precomputed w) to LDS, gathers into
// acc[3][3][CH] (quadrant-static targets, unroll 4), writes s-row to the LDS
// s-tile st[4][KP+8]. Phase 2 (after 1 barrier): wave computes f-cols
// [wave*16, +16) for ALL 4 rows: A-frag = st[lr&3][ks+quad*8] (M=4 padded to
// 16; D row g only uses A row g -> discarded rows harmless), B-frag = Wt row
// (wave*16+lr) from L2. quad==0 lanes store rows 0-3 (+bias, relu, fp16 /
// atomicMax). CH = CIN/64.
template<int CH>
__global__ __launch_bounds__(256, 8) void fused_kernel(
    const _Float16* __restrict__ hsrc,   // [16384][CIN] fp16
    const int* __restrict__ edge_m, const float4* __restrict__ edge_w,
    const int4* __restrict__ cnt4,
    const float* __restrict__ deginv,
    const _Float16* __restrict__ Wt,     // [64][KP] fp16
    const float* __restrict__ bias,
    _Float16* __restrict__ hout,         // [16384][64] or null
    unsigned int* __restrict__ gmax) {   // [32][64] or null
  const int CIN = 64 * CH, KP = 10 * CIN, SLD = KP + 8;
  __shared__ float4 eshw[4][CAP];
  __shared__ int eshm[4][CAP];
  __shared__ __attribute__((aligned(16))) _Float16 st[4][SLD];
  int wave = threadIdx.x >> 6, lane = threadIdx.x & 63;
  int xcd = blockIdx.x & 7;
  int j = blockIdx.x >> 3;
  int b = xcd * 4 + (j >> 7);
  int n = ((j & 127) << 2) + wave;          // row within batch
  int row = (b << 9) + n;
  int rowbase = row - wave;                 // first of the block's 4 rows
  int4 c4 = cnt4[row];
  int e1 = c4.x, e2 = e1 + c4.y, e3 = e2 + c4.z, e4 = e3 + c4.w;
  size_t ebase = (size_t)row * CAP;
  for (int i = lane; i < e4; i += 64) {     // wave-private region, no barrier
    eshw[wave][i] = edge_w[ebase + i];
    eshm[wave][i] = edge_m[ebase + i];
  }
  float di = deginv[row];
  const _Float16* hb = hsrc + (size_t)b * N_ * CIN + lane * CH;

  float acc[3][3][CH];
  #pragma unroll
  for (int kx = 0; kx < 3; ++kx)
    #pragma unroll
    for (int ky = 0; ky < 3; ++ky)
      #pragma unroll
      for (int c = 0; c < CH; ++c) acc[kx][ky][c] = 0.0f;

#define EDGE_BODY(E, KX, KY) {                                        \
    int m = eshm[wave][E];                                            \
    float4 wv = eshw[wave][E];                                        \
    float hv[CH];                                                     \
    if (CH == 1) {                                                    \
      hv[0] = (float)hb[(size_t)m * 64];                              \
    } else {                                                          \
      unsigned u = *(const unsigned*)&hb[(size_t)m * 128];            \
      f16x2 hp = __builtin_bit_cast(f16x2, u);                        \
      hv[0] = (float)hp[0]; hv[CH - 1] = (float)hp[1];                \
    }                                                                 \
    _Pragma("unroll")                                                 \
    for (int c = 0; c < CH; ++c) {                                    \
      acc[KX][KY][c]         += wv.x * hv[c];                         \
      acc[KX][KY + 1][c]     += wv.y * hv[c];                         \
      acc[KX + 1][KY][c]     += wv.z * hv[c];                         \
      acc[KX + 1][KY + 1][c] += wv.w * hv[c];                         \
    } }

  #pragma unroll 4
  for (int e = 0; e < e1; ++e) EDGE_BODY(e, 0, 0)    // quad0: kx0=0, ky0=0
  #pragma unroll 4
  for (int e = e1; e < e2; ++e) EDGE_BODY(e, 1, 0)   // quad1: kx0=1, ky0=0
  #pragma unroll 4
  for (int e = e2; e < e3; ++e) EDGE_BODY(e, 0, 1)   // quad2: kx0=0, ky0=1
  #pragma unroll 4
  for (int e = e3; e < e4; ++e) EDGE_BODY(e, 1, 1)   // quad3: kx0=1, ky0=1
#undef EDGE_BODY

  // store s-row to the LDS s-tile: col k*CIN + lane*CH, k = kx*3 + ky
  #pragma unroll
  for (int kx = 0; kx < 3; ++kx)
    #pragma unroll
    for (int ky = 0; ky < 3; ++ky) {
      int k = kx * 3 + ky;
      if (CH == 1) {
        st[wave][k * CIN + lane] = (_Float16)(acc[kx][ky][0] * di);
      } else {
        f16x2 p;
        p[0] = (_Float16)(acc[kx][ky][0] * di);
        p[1] = (_Float16)(acc[kx][ky][CH - 1] * di);
        *(f16x2*)&st[wave][k * CIN + lane * CH] = p;
      }
    }
  // root column: h passthrough
  if (CH == 1) {
    st[wave][9 * CIN + lane] = hb[(size_t)n * 64];
  } else {
    *(unsigned*)&st[wave][9 * CIN + lane * 2] = *(const unsigned*)&hb[(size_t)n * 128];
  }
  __syncthreads();

  // ---- phase 2: projection via MFMA; wave owns f-cols [wave*16, +16) ----
  int lr = lane & 15, quad = lane >> 4;
  int fcol = (wave << 4) + lr;
  const _Float16* wrow = Wt + (size_t)fcol * KP + quad * 8;
  const _Float16* arow = &st[lr & 3][quad * 8];
  f32x4 oacc = {0.f, 0.f, 0.f, 0.f};
  #pragma unroll 4
  for (int ks = 0; ks < KP; ks += 32) {
    f16x8 af = *(const f16x8*)(arow + ks);
    f16x8 bf = *(const f16x8*)(wrow + ks);
    oacc = __builtin_amdgcn_mfma_f32_16x16x32_f16(af, bf, oacc, 0, 0, 0);
  }
  // D row g uses only A row g; A row g = st[g&3] -> lane reg r = out row r.
  if (quad == 0) {
    float bs = bias[fcol];
    float vmax = 0.0f;
    #pragma unroll
    for (int r = 0; r < 4; ++r) {
      float v = fmaxf(oacc[r] + bs, 0.0f);
      if (hout) hout[(size_t)(rowbase + r) * F_ + fcol] = (_Float16)v;
      vmax = fmaxf(vmax, v);
    }
    if (gmax) atomicMax(&gmax[(b << 6) + fcol], __float_as_uint(vmax));
  }
}

// ---------------- FC from pooled features ----------------
__global__ __launch_bounds__(64) void fc_kernel(
    const float* __restrict__ g, const float* __restrict__ fcw,
    const float* __restrict__ fcb, float* __restrict__ out) {
  int b = blockIdx.x;
  int f = threadIdx.x;
  __shared__ float gs[64];
  gs[f] = g[b * F_ + f];
  __syncthreads();
  if (f < 10) {
    float s = fcb[f];
    #pragma unroll
    for (int c = 0; c < 64; ++c) s += gs[c] * fcw[c * 10 + f];
    out[b * 10 + f] = s;
  }
}

extern "C" void kernel_launch(void* const* d_in, const int* in_sizes, int n_in,
                              void* d_out, int out_size, void* d_ws, size_t ws_size,
                              hipStream_t stream) {
  const float* x     = (const float*)d_in[0];
  const float* coord = (const float*)d_in[1];
  const float* adj   = (const float*)d_in[2];
  const float* w0    = (const float*)d_in[3];
  const float* root0 = (const float*)d_in[4];
  const float* b0    = (const float*)d_in[5];
  const float* w1    = (const float*)d_in[6];
  const float* root1 = (const float*)d_in[7];
  const float* b1    = (const float*)d_in[8];
  const float* w2    = (const float*)d_in[9];
  const float* root2 = (const float*)d_in[10];
  const float* b2    = (const float*)d_in[11];
  const float* fcw   = (const float*)d_in[12];
  const float* fcb   = (const float*)d_in[13];
  float* out = (float*)d_out;

  char* ws = (char*)d_ws;
  size_t off = 0;
  auto alloc = [&](size_t bytes) {
    void* p = ws + off;
    off = (off + bytes + 255) & ~(size_t)255;
    return p;
  };
  const int R = B_ * N_;  // 16384
  int*    edge_m  = (int*)   alloc((size_t)R * CAP * 4);
  float4* edge_w  = (float4*)alloc((size_t)R * CAP * 16);
  int4*   cnt4    = (int4*)  alloc((size_t)R * 16);
  float*  deginv  = (float*) alloc((size_t)R * 4);
  _Float16* hx    = (_Float16*)alloc((size_t)R * 128 * 2);   // fp16 x
  _Float16* wt0   = (_Float16*)alloc((size_t)64 * 1280 * 2);
  _Float16* wt1   = (_Float16*)alloc((size_t)64 * 640 * 2);
  _Float16* wt2   = (_Float16*)alloc((size_t)64 * 640 * 2);
  _Float16* hA    = (_Float16*)alloc((size_t)R * 64 * 2);
  _Float16* hB    = (_Float16*)alloc((size_t)R * 64 * 2);
  unsigned int* gmax = (unsigned int*)alloc((size_t)B_ * F_ * 4);

  preprocess_kernel<<<R / 8, 512, 0, stream>>>(
      adj, coord, edge_m, edge_w, cnt4, deginv, gmax,
      x, hx, w0, root0, w1, root1, w2, root2, wt0, wt1, wt2);

  // layer 0: CIN=128, K = 1280
  fused_kernel<2><<<R / 4, 256, 0, stream>>>(hx, edge_m, edge_w, cnt4, deginv,
                                             wt0, b0, hA, nullptr);
  // layer 1: CIN=64, K = 640
  fused_kernel<1><<<R / 4, 256, 0, stream>>>(hA, edge_m, edge_w, cnt4, deginv,
                                             wt1, b1, hB, nullptr);
  // layer 2: CIN=64, K = 640 — fused max-pool
  fused_kernel<1><<<R / 4, 256, 0, stream>>>(hB, edge_m, edge_w, cnt4, deginv,
                                             wt2, b2, nullptr, gmax);

  fc_kernel<<<B_, 64, 0, stream>>>((const float*)gmax, fcw, fcb, out);
}

// Round 18
// 230.547 us; speedup vs baseline: 1.2646x; 1.2646x over previous
//
#include <hip/hip_runtime.h>

// SplineCNN on MI355X — aggregate-before-GEMM, L2-direct gather (R16 base).
//
// Math order: s[n, k*CIN+c] = deginv * sum_{m in N(n)} basis_k(n,m) * h[m,c],
// root column appended -> one dense GEMM per layer:
//   out = relu( [s | h] @ [w; root] + bias ),  K = 10*CIN, N = 64.
// R16 (213.9us best): barrier-free wave-per-row preprocess + lean gather
// (VGPR<=64, 8 waves/SIMD) + precomputed tap weights + split GEMM.
// R7/R17 falsified fusion (per-block Wt re-read 656MB L2 + serial MFMA chain
// + LDS bank conflicts); the split structure stays.
// THIS ROUND: cross-group 2-deep prefetch in the gather (R2-proven pattern,
// never applied to the lean body): per quad-run, issue group g+4's 4 h-loads
// BEFORE consuming group g -> stalls per row ~8 -> ~4-5. Prereq: preprocess
// pads each quad run to x4 with ZERO-weight records (R12-proven, bit-exact:
// 0*h adds nothing; m=0 is a safe address). cnt4 = padded counts; deginv
// uses the true degree. Everything else R16-verbatim.
// All tensors fp16 (fp32 accumulate in gather + MFMA); layer-2 GEMM epilogue
// fuses global max-pool via uint-bitcast atomicMax (relu >= 0).

#define B_   32
#define N_   512
#define F_   64
#define CAP  128          // max padded neighbors (mean ~31 + <=12 pad)

typedef float f32x4 __attribute__((ext_vector_type(4)));
typedef _Float16 f16x8 __attribute__((ext_vector_type(8)));
typedef _Float16 f16x2 __attribute__((ext_vector_type(2)));

// ---------------- preprocess: wave-per-row, barrier-free, x4-padded quads ----------------
// edge_m[row*CAP+i] = neighbor m; edge_w[row*CAP+i] = {w00,w01,w10,w11} f32.
// Sorted by quad = kx0 + 2*ky0, ascending m within quad; each quad run padded
// to x4 with zero records. cnt4[row] = PADDED per-quad counts (cum <= CAP);
// deginv = 1/clip(true_deg,1). Grid 2048 x 512: wave w handles row i*8+w.
// Also merged prep (x fp32->fp16 + pack [w;root] -> Wt fp16) + gmax zeroing.
__global__ __launch_bounds__(512, 8) void preprocess_kernel(
    const float* __restrict__ adj, const float* __restrict__ coord,
    int* __restrict__ edge_m, float4* __restrict__ edge_w,
    int4* __restrict__ cnt4,
    float* __restrict__ deginv, unsigned int* __restrict__ gmax,
    const float* __restrict__ x, _Float16* __restrict__ hx,
    const float* __restrict__ w0, const float* __restrict__ root0,
    const float* __restrict__ w1, const float* __restrict__ root1,
    const float* __restrict__ w2, const float* __restrict__ root2,
    _Float16* __restrict__ wt0, _Float16* __restrict__ wt1,
    _Float16* __restrict__ wt2) {
  int tid = threadIdx.x, wave = tid >> 6, lane = tid & 63;
  if (tid == 0) gmax[blockIdx.x] = 0u;   // grid 2048 == B_*F_

  // ---- merged prep: idx space [0, R*32) convx; then packw for 3 layers ----
  {
    int idx = blockIdx.x * 512 + tid;    // covers 1,048,576 >= 688,128
    const int CX = B_ * N_ * 32;
    const int S0 = 64 * 1280, S1 = 64 * 640;
    if (idx < CX) {
      float4 v = ((const float4*)x)[idx];
      f16x2 p0, p1;
      p0[0] = (_Float16)v.x; p0[1] = (_Float16)v.y;
      p1[0] = (_Float16)v.z; p1[1] = (_Float16)v.w;
      uint2 u;
      u.x = __builtin_bit_cast(unsigned, p0);
      u.y = __builtin_bit_cast(unsigned, p1);
      ((uint2*)hx)[idx] = u;
    } else if (idx < CX + S0 + 2 * S1) {
      int r = idx - CX;
      const float *w, *root; _Float16* wt; int KP, CIN;
      if (r < S0)           { w = w0; root = root0; wt = wt0; KP = 1280; CIN = 128; }
      else if (r < S0 + S1) { w = w1; root = root1; wt = wt1; KP = 640;  CIN = 64;  r -= S0; }
      else                  { w = w2; root = root2; wt = wt2; KP = 640;  CIN = 64;  r -= S0 + S1; }
      int f = r / KP, k = r - f * KP;
      int ks = k / CIN, c = k - ks * CIN;
      float v = (ks < 9) ? w[((size_t)ks * CIN + c) * F_ + f]
                         : root[(size_t)c * F_ + f];
      wt[(size_t)f * KP + k] = (_Float16)v;
    }
  }

  int row = blockIdx.x * 8 + wave;       // one row per wave
  int b = row >> 9;
  float cxn = coord[(size_t)row * 2 + 0];
  float cyn = coord[(size_t)row * 2 + 1];

  // ---- pass 1: load + classify 8 chunks of 64; wave-uniform quad totals ----
  int   pq[8];                  // quad (0..3) or -1 if no edge
  float pfx[8], pfy[8];
  int q0 = 0, q1 = 0, q2 = 0, q3 = 0;
  #pragma unroll
  for (int c = 0; c < 8; ++c) {
    int m = c * 64 + lane;
    float a = adj[(size_t)row * N_ + m];
    bool flag = (a != 0.0f);
    float cxm = coord[(size_t)(b * N_ + m) * 2 + 0];
    float cym = coord[(size_t)(b * N_ + m) * 2 + 1];
    float vx = cxm - cxn + 1.0f;         // = u*2 (K-1 = 2, u in [0,1])
    float vy = cym - cyn + 1.0f;
    float i0x = fminf(fmaxf(floorf(vx), 0.0f), 1.0f);
    float i0y = fminf(fmaxf(floorf(vy), 0.0f), 1.0f);
    pfx[c] = vx - i0x;
    pfy[c] = vy - i0y;
    int quad = (int)i0x + 2 * (int)i0y;  // 0..3
    pq[c] = flag ? quad : -1;
    q0 += __popcll(__ballot(flag && quad == 0));
    q1 += __popcll(__ballot(flag && quad == 1));
    q2 += __popcll(__ballot(flag && quad == 2));
    q3 += __popcll(__ballot(flag && quad == 3));
  }

  // padded layout (each quad run x4; cumulative <= CAP)
  int rem = CAP;
  int c0 = min(q0, rem); int c0p = min((c0 + 3) & ~3, rem); rem -= c0p;
  int c1 = min(q1, rem); int c1p = min((c1 + 3) & ~3, rem); rem -= c1p;
  int c2 = min(q2, rem); int c2p = min((c2 + 3) & ~3, rem); rem -= c2p;
  int c3 = min(q3, rem); int c3p = min((c3 + 3) & ~3, rem);
  c0 = min(c0, c0p); c1 = min(c1, c1p); c2 = min(c2, c2p); c3 = min(c3, c3p);
  int B1 = c0p, B2 = c0p + c1p, B3 = B2 + c2p;
  int L0 = c0, L1 = B1 + c1, L2 = B2 + c2, L3 = B3 + c3;  // write limits

  // ---- pass 2: running per-quad offsets -> quad-sorted edge writes ----
  int ro0 = 0, ro1 = B1, ro2 = B2, ro3 = B3;   // quad running offsets
  #pragma unroll
  for (int c = 0; c < 8; ++c) {
    unsigned long long b0 = __ballot(pq[c] == 0);
    unsigned long long b1 = __ballot(pq[c] == 1);
    unsigned long long b2 = __ballot(pq[c] == 2);
    unsigned long long b3 = __ballot(pq[c] == 3);
    int q = pq[c];
    if (q >= 0) {
      unsigned long long myb = (q == 0) ? b0 : (q == 1) ? b1 : (q == 2) ? b2 : b3;
      int base = (q == 0) ? ro0 : (q == 1) ? ro1 : (q == 2) ? ro2 : ro3;
      int lim  = (q == 0) ? L0  : (q == 1) ? L1  : (q == 2) ? L2  : L3;
      int off = base + __popcll(myb & ((1ULL << lane) - 1ULL));
      if (off < lim) {
        float fx = pfx[c], fy = pfy[c];
        float gx = 1.0f - fx, gy = 1.0f - fy;
        edge_m[(size_t)row * CAP + off] = c * 64 + lane;
        edge_w[(size_t)row * CAP + off] =
            make_float4(gx * gy, gx * fy, fx * gy, fx * fy);
      }
    }
    ro0 += __popcll(b0); ro1 += __popcll(b1);
    ro2 += __popcll(b2); ro3 += __popcll(b3);
  }
  // zero-fill pad slots (<=3 per quad): lanes 0-15, q = lane>>2, i = lane&3
  if (lane < 16) {
    int q = lane >> 2, i = lane & 3;
    int cq  = (q == 0) ? c0  : (q == 1) ? c1  : (q == 2) ? c2  : c3;
    int cqp = (q == 0) ? c0p : (q == 1) ? c1p : (q == 2) ? c2p : c3p;
    int Bq  = (q == 0) ? 0   : (q == 1) ? B1  : (q == 2) ? B2  : B3;
    if (cq + i < cqp) {
      edge_m[(size_t)row * CAP + Bq + cq + i] = 0;
      edge_w[(size_t)row * CAP + Bq + cq + i] = make_float4(0.f, 0.f, 0.f, 0.f);
    }
  }
  if (lane == 0) {
    cnt4[row] = make_int4(c0p, c1p, c2p, c3p);
    int total = q0 + q1 + q2 + q3;
    deginv[row] = 1.0f / (float)(total > 0 ? total : 1);
  }
}

// ---------------- gather: s[row, k*CIN + c] = deginv * sum basis_k * h[m,c] ----------------
// 256 threads = 4 waves, ONE ROW PER WAVE; grid 4096, XCD-swizzled so batch b's
// blocks share an XCD (h slice <=512KB L2-resident). Wave stages its row's edge
// list (m + precomputed weights) to LDS, then per quad-run (x4-padded):
// 2-DEEP CROSS-GROUP PIPELINE — prologue-load group g's 4 h-values, loop
// {issue g+4's loads; consume g}. Stalls per row ~8 -> ~4-5 while staying
// within the VGPR<=64 budget (launch_bounds(256,8), 8 waves/SIMD).
// Quadrant runs give static accumulator targets. CH = CIN/64 channels/lane.
template<int CH>
__global__ __launch_bounds__(256, 8) void gather_kernel(
    const _Float16* __restrict__ hsrc,   // [16384][CIN] fp16
    const int* __restrict__ edge_m, const float4* __restrict__ edge_w,
    const int4* __restrict__ cnt4,
    const float* __restrict__ deginv,
    _Float16* __restrict__ sp) {         // [16384][KP]
  const int CIN = 64 * CH, KP = 10 * CIN;
  __shared__ float4 eshw[4][CAP];
  __shared__ int eshm[4][CAP];
  int wave = threadIdx.x >> 6, lane = threadIdx.x & 63;
  int xcd = blockIdx.x & 7;
  int j = blockIdx.x >> 3;
  int b = xcd * 4 + (j >> 7);
  int n = ((j & 127) << 2) + wave;          // row within batch
  int row = (b << 9) + n;
  int4 c4 = cnt4[row];                      // padded counts (x4 each)
  int e1 = c4.x, e2 = e1 + c4.y, e3 = e2 + c4.z, e4 = e3 + c4.w;
  size_t ebase = (size_t)row * CAP;
  for (int i = lane; i < e4; i += 64) {     // wave-private region, no barrier
    eshw[wave][i] = edge_w[ebase + i];
    eshm[wave][i] = edge_m[ebase + i];
  }
  float di = deginv[row];
  const _Float16* hb = hsrc + (size_t)b * N_ * CIN + lane * CH;

  float acc[3][3][CH];
  #pragma unroll
  for (int kx = 0; kx < 3; ++kx)
    #pragma unroll
    for (int ky = 0; ky < 3; ++ky)
      #pragma unroll
      for (int c = 0; c < CH; ++c) acc[kx][ky][c] = 0.0f;

  // load 4 h-values for edge group G into P regs (unsigned; CH=1 zero-ext u16)
#define LOADH(P, G) {                                                 \
    int m0 = eshm[wave][(G) + 0];                                     \
    int m1 = eshm[wave][(G) + 1];                                     \
    int m2 = eshm[wave][(G) + 2];                                     \
    int m3 = eshm[wave][(G) + 3];                                     \
    if (CH == 1) {                                                    \
      P##0 = *(const unsigned short*)&hb[(size_t)m0 * 64];            \
      P##1 = *(const unsigned short*)&hb[(size_t)m1 * 64];            \
      P##2 = *(const unsigned short*)&hb[(size_t)m2 * 64];            \
      P##3 = *(const unsigned short*)&hb[(size_t)m3 * 64];            \
    } else {                                                          \
      P##0 = *(const unsigned*)&hb[(size_t)m0 * 128];                 \
      P##1 = *(const unsigned*)&hb[(size_t)m1 * 128];                 \
      P##2 = *(const unsigned*)&hb[(size_t)m2 * 128];                 \
      P##3 = *(const unsigned*)&hb[(size_t)m3 * 128];                 \
    } }

#define CONS1(U, E, KX, KY) {                                         \
    float4 wv = eshw[wave][E];                                        \
    float hv[CH];                                                     \
    if (CH == 1) {                                                    \
      hv[0] = (float)__builtin_bit_cast(_Float16, (unsigned short)(U));\
    } else {                                                          \
      f16x2 hp = __builtin_bit_cast(f16x2, (unsigned)(U));            \
      hv[0] = (float)hp[0]; hv[CH - 1] = (float)hp[1];                \
    }                                                                 \
    _Pragma("unroll")                                                 \
    for (int c = 0; c < CH; ++c) {                                    \
      acc[KX][KY][c]         += wv.x * hv[c];                         \
      acc[KX][KY + 1][c]     += wv.y * hv[c];                         \
      acc[KX + 1][KY][c]     += wv.z * hv[c];                         \
      acc[KX + 1][KY + 1][c] += wv.w * hv[c];                         \
    } }

#define CONSG(P, G, KX, KY) {                                         \
    CONS1(P##0, (G) + 0, KX, KY); CONS1(P##1, (G) + 1, KX, KY);       \
    CONS1(P##2, (G) + 2, KX, KY); CONS1(P##3, (G) + 3, KX, KY); }

  // per-quad 2-deep pipelined loop (runs are x4-padded; pads have w=0)
#define QUAD_LOOP(QS, QE, KX, KY) {                                   \
    int g = (QS);                                                     \
    if (g < (QE)) {                                                   \
      unsigned A0, A1, A2, A3, B0, B1, B2, B3;                        \
      LOADH(A, g);                                                    \
      for (; g + 4 < (QE); g += 4) {                                  \
        LOADH(B, g + 4);                                              \
        CONSG(A, g, KX, KY);                                          \
        A0 = B0; A1 = B1; A2 = B2; A3 = B3;                           \
      }                                                               \
      CONSG(A, g, KX, KY);                                            \
    } }

  QUAD_LOOP(0, e1, 0, 0)    // quad0: kx0=0, ky0=0
  QUAD_LOOP(e1, e2, 1, 0)   // quad1: kx0=1, ky0=0
  QUAD_LOOP(e2, e3, 0, 1)   // quad2: kx0=0, ky0=1
  QUAD_LOOP(e3, e4, 1, 1)   // quad3: kx0=1, ky0=1
#undef QUAD_LOOP
#undef CONSG
#undef CONS1
#undef LOADH

  // store: k = kx*3 + ky (reference reshape order); cols k*CIN + lane*CH
  _Float16* sr = sp + (size_t)row * KP + lane * CH;
  #pragma unroll
  for (int kx = 0; kx < 3; ++kx)
    #pragma unroll
    for (int ky = 0; ky < 3; ++ky) {
      int k = kx * 3 + ky;
      if (CH == 1) {
        sr[(size_t)k * CIN] = (_Float16)(acc[kx][ky][0] * di);
      } else {
        f16x2 p;
        p[0] = (_Float16)(acc[kx][ky][0] * di);
        p[1] = (_Float16)(acc[kx][ky][CH - 1] * di);
        *(f16x2*)&sr[(size_t)k * CIN] = p;
      }
    }
  // root column: h passthrough
  if (CH == 1) {
    sr[(size_t)9 * CIN] = hb[(size_t)n * 64];
  } else {
    *(unsigned*)&sr[(size_t)9 * CIN] = *(const unsigned*)&hb[(size_t)n * 128];
  }
}

// ---------------- dense GEMM: out[m,f] = relu( A[m,:]@Wt[f,:] + bias[f] ) ----------------
// A fp16 [16384][KP], Wt fp16 [64][KP]. M-tile 64 (grid 256), 256 thr = 4 waves,
// wave owns 16 rows x 64 cols, 16x16x32 f16 MFMA. Double-buffered LDS with
// issue-early/write-late staging (T14). Epilogue: fp16 h-out and/or fused
// max-pool (atomicMax on uint bits, relu >= 0).
#define GBK  64
#define GLDK 72
__global__ __launch_bounds__(256) void gemm_s_kernel(
    const _Float16* __restrict__ A, const _Float16* __restrict__ Wt,
    const float* __restrict__ bias, _Float16* __restrict__ hout,
    unsigned int* __restrict__ gmax, int KP) {
  __shared__ __attribute__((aligned(16))) _Float16 As[2][64 * GLDK];
  __shared__ __attribute__((aligned(16))) _Float16 Ws[2][64 * GLDK];
  int bm = blockIdx.x << 6;
  int tid = threadIdx.x, wave = tid >> 6, lane = tid & 63;
  int lr = lane & 15, quad = lane >> 4;
  int srow = tid >> 3, sck = (tid & 7) * 8;       // staging: rows srow, srow+32
  const size_t aoff = (size_t)(bm + srow) * KP + sck;
  const size_t woff = (size_t)srow * KP + sck;

  f32x4 acc[4] = {};
  // stage step 0 directly
  {
    *(float4*)&As[0][srow * GLDK + sck]        = *(const float4*)&A[aoff];
    *(float4*)&As[0][(srow + 32) * GLDK + sck] = *(const float4*)&A[aoff + (size_t)32 * KP];
    *(float4*)&Ws[0][srow * GLDK + sck]        = *(const float4*)&Wt[woff];
    *(float4*)&Ws[0][(srow + 32) * GLDK + sck] = *(const float4*)&Wt[woff + (size_t)32 * KP];
  }
  int S = KP / GBK, cur = 0;
  float4 pa0, pa1, pw0, pw1;
  for (int s = 0; s < S; ++s) {
    if (s + 1 < S) {                 // issue next tile's loads (no wait)
      int k0 = (s + 1) * GBK;
      pa0 = *(const float4*)&A[aoff + k0];
      pa1 = *(const float4*)&A[aoff + (size_t)32 * KP + k0];
      pw0 = *(const float4*)&Wt[woff + k0];
      pw1 = *(const float4*)&Wt[woff + (size_t)32 * KP + k0];
    }
    __syncthreads();                 // buf[cur] ready for all waves
    #pragma unroll
    for (int kk = 0; kk < GBK; kk += 32) {
      f16x8 af = *(const f16x8*)&As[cur][(16 * wave + lr) * GLDK + kk + quad * 8];
      #pragma unroll
      for (int j = 0; j < 4; ++j) {
        f16x8 bf = *(const f16x8*)&Ws[cur][(16 * j + lr) * GLDK + kk + quad * 8];
        acc[j] = __builtin_amdgcn_mfma_f32_16x16x32_f16(af, bf, acc[j], 0, 0, 0);
      }
    }
    if (s + 1 < S) {                 // write-late into the other buffer
      int nb = cur ^ 1;
      *(float4*)&As[nb][srow * GLDK + sck]        = pa0;
      *(float4*)&As[nb][(srow + 32) * GLDK + sck] = pa1;
      *(float4*)&Ws[nb][srow * GLDK + sck]        = pw0;
      *(float4*)&Ws[nb][(srow + 32) * GLDK + sck] = pw1;
    }
    cur ^= 1;
  }
  // epilogue: C layout col = lane&15, row = quad*4 + r (verified)
  int b = bm >> 9;
  #pragma unroll
  for (int j = 0; j < 4; ++j) {
    int f = 16 * j + lr;
    float bs = bias[f];
    float vmax = 0.0f;
    #pragma unroll
    for (int r = 0; r < 4; ++r) {
      int m = bm + (wave << 4) + (quad << 2) + r;
      float v = fmaxf(acc[j][r] + bs, 0.0f);
      if (hout) hout[(size_t)m * F_ + f] = (_Float16)v;
      vmax = fmaxf(vmax, v);
    }
    if (gmax) atomicMax(&gmax[(b << 6) + f], __float_as_uint(vmax));
  }
}

// ---------------- FC from pooled features ----------------
__global__ __launch_bounds__(64) void fc_kernel(
    const float* __restrict__ g, const float* __restrict__ fcw,
    const float* __restrict__ fcb, float* __restrict__ out) {
  int b = blockIdx.x;
  int f = threadIdx.x;
  __shared__ float gs[64];
  gs[f] = g[b * F_ + f];
  __syncthreads();
  if (f < 10) {
    float s = fcb[f];
    #pragma unroll
    for (int c = 0; c < 64; ++c) s += gs[c] * fcw[c * 10 + f];
    out[b * 10 + f] = s;
  }
}

extern "C" void kernel_launch(void* const* d_in, const int* in_sizes, int n_in,
                              void* d_out, int out_size, void* d_ws, size_t ws_size,
                              hipStream_t stream) {
  const float* x     = (const float*)d_in[0];
  const float* coord = (const float*)d_in[1];
  const float* adj   = (const float*)d_in[2];
  const float* w0    = (const float*)d_in[3];
  const float* root0 = (const float*)d_in[4];
  const float* b0    = (const float*)d_in[5];
  const float* w1    = (const float*)d_in[6];
  const float* root1 = (const float*)d_in[7];
  const float* b1    = (const float*)d_in[8];
  const float* w2    = (const float*)d_in[9];
  const float* root2 = (const float*)d_in[10];
  const float* b2    = (const float*)d_in[11];
  const float* fcw   = (const float*)d_in[12];
  const float* fcb   = (const float*)d_in[13];
  float* out = (float*)d_out;

  char* ws = (char*)d_ws;
  size_t off = 0;
  auto alloc = [&](size_t bytes) {
    void* p = ws + off;
    off = (off + bytes + 255) & ~(size_t)255;
    return p;
  };
  const int R = B_ * N_;  // 16384
  int*    edge_m  = (int*)   alloc((size_t)R * CAP * 4);
  float4* edge_w  = (float4*)alloc((size_t)R * CAP * 16);
  int4*   cnt4    = (int4*)  alloc((size_t)R * 16);
  float*  deginv  = (float*) alloc((size_t)R * 4);
  _Float16* hx    = (_Float16*)alloc((size_t)R * 128 * 2);   // fp16 x
  _Float16* wt0   = (_Float16*)alloc((size_t)64 * 1280 * 2);
  _Float16* wt1   = (_Float16*)alloc((size_t)64 * 640 * 2);
  _Float16* wt2   = (_Float16*)alloc((size_t)64 * 640 * 2);
  _Float16* sp    = (_Float16*)alloc((size_t)R * 1280 * 2);  // s (max K)
  _Float16* hA    = (_Float16*)alloc((size_t)R * 64 * 2);
  _Float16* hB    = (_Float16*)alloc((size_t)R * 64 * 2);
  unsigned int* gmax = (unsigned int*)alloc((size_t)B_ * F_ * 4);

  preprocess_kernel<<<R / 8, 512, 0, stream>>>(
      adj, coord, edge_m, edge_w, cnt4, deginv, gmax,
      x, hx, w0, root0, w1, root1, w2, root2, wt0, wt1, wt2);

  // layer 0: CIN=128, K = 1280
  gather_kernel<2><<<R / 4, 256, 0, stream>>>(hx, edge_m, edge_w, cnt4, deginv, sp);
  gemm_s_kernel<<<R / 64, 256, 0, stream>>>(sp, wt0, b0, hA, nullptr, 1280);

  // layer 1: CIN=64, K = 640
  gather_kernel<1><<<R / 4, 256, 0, stream>>>(hA, edge_m, edge_w, cnt4, deginv, sp);
  gemm_s_kernel<<<R / 64, 256, 0, stream>>>(sp, wt1, b1, hB, nullptr, 640);

  // layer 2: CIN=64, K = 640 — fused max-pool
  gather_kernel<1><<<R / 4, 256, 0, stream>>>(hB, edge_m, edge_w, cnt4, deginv, sp);
  gemm_s_kernel<<<R / 64, 256, 0, stream>>>(sp, wt2, b2, nullptr, gmax, 640);

  fc_kernel<<<B_, 64, 0, stream>>>((const float*)gmax, fcw, fcb, out);
}

// Round 19
// 213.637 us; speedup vs baseline: 1.3647x; 1.0792x over previous
//
#include <hip/hip_runtime.h>

// SplineCNN on MI355X — aggregate-before-GEMM, L2-direct gather (R16 final).
//
// Math order: s[n, k*CIN+c] = deginv * sum_{m in N(n)} basis_k(n,m) * h[m,c],
// root column appended -> one dense GEMM per layer:
//   out = relu( [s | h] @ [w; root] + bias ),  K = 10*CIN, N = 64.
// Measured best (213.9us). Design ledger:
//  - gather: lean body, VGPR<=64 via launch_bounds(256,8) -> 8 waves/SIMD
//    (R13 +4us); precomputed tap weights in edge_w (R14 +7us). Deeper
//    pipelines/unrolls all spill or halve occupancy (R8/R11/R18 falsified);
//    slot-parallel (R12), fusion (R7/R17), quadrant-per-wave (R10) falsified.
//  - preprocess: barrier-free wave-per-row, two ballot passes, no LDS
//    (R16 +15us); merged with x->fp16 convert + weight pack + gmax zero.
//  - GEMM: M-tile 64, 16x16x32 f16 MFMA, double-buffered LDS (T14 staging).
//  - XCD swizzle everywhere: batch b's blocks on XCD b>>2 (h L2-resident).
// All tensors fp16 (fp32 accumulate in gather + MFMA); layer-2 GEMM epilogue
// fuses global max-pool via uint-bitcast atomicMax (relu >= 0).

#define B_   32
#define N_   512
#define F_   64
#define CAP  128          // max neighbors per node (mean ~31; P(>128) ~ 18 sigma)

typedef float f32x4 __attribute__((ext_vector_type(4)));
typedef _Float16 f16x8 __attribute__((ext_vector_type(8)));
typedef _Float16 f16x2 __attribute__((ext_vector_type(2)));

// ---------------- preprocess: wave-per-row, barrier-free ----------------
// edge_m[row*CAP+i] = neighbor index m; edge_w[row*CAP+i] = {w00,w01,w10,w11}
// (bilinear tap weights, f32, precomputed). Sorted by quad = kx0 + 2*ky0,
// ascending m within each quad. cnt4[row] = clamped cumulative quad counts;
// deginv = 1/clip(deg,1). Grid 2048 x 512: wave w of block i handles row
// i*8+w. Also merged prep (x fp32->fp16 + pack [w;root] -> Wt) + gmax zero.
__global__ __launch_bounds__(512, 8) void preprocess_kernel(
    const float* __restrict__ adj, const float* __restrict__ coord,
    int* __restrict__ edge_m, float4* __restrict__ edge_w,
    int4* __restrict__ cnt4,
    float* __restrict__ deginv, unsigned int* __restrict__ gmax,
    const float* __restrict__ x, _Float16* __restrict__ hx,
    const float* __restrict__ w0, const float* __restrict__ root0,
    const float* __restrict__ w1, const float* __restrict__ root1,
    const float* __restrict__ w2, const float* __restrict__ root2,
    _Float16* __restrict__ wt0, _Float16* __restrict__ wt1,
    _Float16* __restrict__ wt2) {
  int tid = threadIdx.x, wave = tid >> 6, lane = tid & 63;
  if (tid == 0) gmax[blockIdx.x] = 0u;   // grid 2048 == B_*F_

  // ---- merged prep: idx space [0, R*32) convx; then packw for 3 layers ----
  {
    int idx = blockIdx.x * 512 + tid;    // covers 1,048,576 >= 688,128
    const int CX = B_ * N_ * 32;
    const int S0 = 64 * 1280, S1 = 64 * 640;
    if (idx < CX) {
      float4 v = ((const float4*)x)[idx];
      f16x2 p0, p1;
      p0[0] = (_Float16)v.x; p0[1] = (_Float16)v.y;
      p1[0] = (_Float16)v.z; p1[1] = (_Float16)v.w;
      uint2 u;
      u.x = __builtin_bit_cast(unsigned, p0);
      u.y = __builtin_bit_cast(unsigned, p1);
      ((uint2*)hx)[idx] = u;
    } else if (idx < CX + S0 + 2 * S1) {
      int r = idx - CX;
      const float *w, *root; _Float16* wt; int KP, CIN;
      if (r < S0)           { w = w0; root = root0; wt = wt0; KP = 1280; CIN = 128; }
      else if (r < S0 + S1) { w = w1; root = root1; wt = wt1; KP = 640;  CIN = 64;  r -= S0; }
      else                  { w = w2; root = root2; wt = wt2; KP = 640;  CIN = 64;  r -= S0 + S1; }
      int f = r / KP, k = r - f * KP;
      int ks = k / CIN, c = k - ks * CIN;
      float v = (ks < 9) ? w[((size_t)ks * CIN + c) * F_ + f]
                         : root[(size_t)c * F_ + f];
      wt[(size_t)f * KP + k] = (_Float16)v;
    }
  }

  int row = blockIdx.x * 8 + wave;       // one row per wave
  int b = row >> 9;
  float cxn = coord[(size_t)row * 2 + 0];
  float cyn = coord[(size_t)row * 2 + 1];

  // ---- pass 1: load + classify 8 chunks of 64; wave-uniform quad totals ----
  int   pq[8];                  // quad (0..3) or -1 if no edge
  float pfx[8], pfy[8];
  int q0 = 0, q1 = 0, q2 = 0, q3 = 0;
  #pragma unroll
  for (int c = 0; c < 8; ++c) {
    int m = c * 64 + lane;
    float a = adj[(size_t)row * N_ + m];
    bool flag = (a != 0.0f);
    float cxm = coord[(size_t)(b * N_ + m) * 2 + 0];
    float cym = coord[(size_t)(b * N_ + m) * 2 + 1];
    float vx = cxm - cxn + 1.0f;         // = u*2 (K-1 = 2, u in [0,1])
    float vy = cym - cyn + 1.0f;
    float i0x = fminf(fmaxf(floorf(vx), 0.0f), 1.0f);
    float i0y = fminf(fmaxf(floorf(vy), 0.0f), 1.0f);
    pfx[c] = vx - i0x;
    pfy[c] = vy - i0y;
    int quad = (int)i0x + 2 * (int)i0y;  // 0..3
    pq[c] = flag ? quad : -1;
    q0 += __popcll(__ballot(flag && quad == 0));
    q1 += __popcll(__ballot(flag && quad == 1));
    q2 += __popcll(__ballot(flag && quad == 2));
    q3 += __popcll(__ballot(flag && quad == 3));
  }
  int qt0 = q0, qt1 = q0 + q1, qt2 = qt1 + q2, qt3 = qt2 + q3;

  // ---- pass 2: running per-quad offsets -> quad-sorted edge writes ----
  int ro0 = 0, ro1 = qt0, ro2 = qt1, ro3 = qt2;   // quad base offsets
  #pragma unroll
  for (int c = 0; c < 8; ++c) {
    unsigned long long b0 = __ballot(pq[c] == 0);
    unsigned long long b1 = __ballot(pq[c] == 1);
    unsigned long long b2 = __ballot(pq[c] == 2);
    unsigned long long b3 = __ballot(pq[c] == 3);
    int q = pq[c];
    if (q >= 0) {
      unsigned long long myb = (q == 0) ? b0 : (q == 1) ? b1 : (q == 2) ? b2 : b3;
      int base = (q == 0) ? ro0 : (q == 1) ? ro1 : (q == 2) ? ro2 : ro3;
      int off = base + __popcll(myb & ((1ULL << lane) - 1ULL));
      if (off < CAP) {
        float fx = pfx[c], fy = pfy[c];
        float gx = 1.0f - fx, gy = 1.0f - fy;
        edge_m[(size_t)row * CAP + off] = c * 64 + lane;
        edge_w[(size_t)row * CAP + off] =
            make_float4(gx * gy, gx * fy, fx * gy, fx * fy);
      }
    }
    ro0 += __popcll(b0); ro1 += __popcll(b1);
    ro2 += __popcll(b2); ro3 += __popcll(b3);
  }
  if (lane == 0) {
    int C0 = min(qt0, CAP), C1 = min(qt1, CAP);
    int C2 = min(qt2, CAP), C3c = min(qt3, CAP);
    cnt4[row] = make_int4(C0, C1 - C0, C2 - C1, C3c - C2);
    deginv[row] = 1.0f / (float)(qt3 > 0 ? qt3 : 1);
  }
}

// ---------------- gather: s[row, k*CIN + c] = deginv * sum basis_k * h[m,c] ----------------
// 256 threads = 4 waves, ONE ROW PER WAVE; grid 4096, XCD-swizzled so batch b's
// blocks share an XCD (h slice <=512KB L2-resident). Wave stages its row's edge
// list (m + precomputed weights) to LDS, then hot loop: 2 broadcast LDS reads
// + contiguous 128/256B global h gather (L2 hit) + 2 cvt + 4*CH FMAs, unroll 4.
// __launch_bounds__(256,8) pins VGPR <= 64 (8 waves/SIMD; lean body fits).
// Quadrant runs give static accumulator targets. CH = CIN/64 channels/lane.
template<int CH>
__global__ __launch_bounds__(256, 8) void gather_kernel(
    const _Float16* __restrict__ hsrc,   // [16384][CIN] fp16
    const int* __restrict__ edge_m, const float4* __restrict__ edge_w,
    const int4* __restrict__ cnt4,
    const float* __restrict__ deginv,
    _Float16* __restrict__ sp) {         // [16384][KP]
  const int CIN = 64 * CH, KP = 10 * CIN;
  __shared__ float4 eshw[4][CAP];
  __shared__ int eshm[4][CAP];
  int wave = threadIdx.x >> 6, lane = threadIdx.x & 63;
  int xcd = blockIdx.x & 7;
  int j = blockIdx.x >> 3;
  int b = xcd * 4 + (j >> 7);
  int n = ((j & 127) << 2) + wave;          // row within batch
  int row = (b << 9) + n;
  int4 c4 = cnt4[row];
  int e1 = c4.x, e2 = e1 + c4.y, e3 = e2 + c4.z, e4 = e3 + c4.w;
  size_t ebase = (size_t)row * CAP;
  for (int i = lane; i < e4; i += 64) {     // wave-private region, no barrier
    eshw[wave][i] = edge_w[ebase + i];
    eshm[wave][i] = edge_m[ebase + i];
  }
  float di = deginv[row];
  const _Float16* hb = hsrc + (size_t)b * N_ * CIN + lane * CH;

  float acc[3][3][CH];
  #pragma unroll
  for (int kx = 0; kx < 3; ++kx)
    #pragma unroll
    for (int ky = 0; ky < 3; ++ky)
      #pragma unroll
      for (int c = 0; c < CH; ++c) acc[kx][ky][c] = 0.0f;

#define EDGE_BODY(E, KX, KY) {                                        \
    int m = eshm[wave][E];                                            \
    float4 wv = eshw[wave][E];                                        \
    float hv[CH];                                                     \
    if (CH == 1) {                                                    \
      hv[0] = (float)hb[(size_t)m * 64];                              \
    } else {                                                          \
      unsigned u = *(const unsigned*)&hb[(size_t)m * 128];            \
      f16x2 hp = __builtin_bit_cast(f16x2, u);                        \
      hv[0] = (float)hp[0]; hv[CH - 1] = (float)hp[1];                \
    }                                                                 \
    _Pragma("unroll")                                                 \
    for (int c = 0; c < CH; ++c) {                                    \
      acc[KX][KY][c]         += wv.x * hv[c];                         \
      acc[KX][KY + 1][c]     += wv.y * hv[c];                         \
      acc[KX + 1][KY][c]     += wv.z * hv[c];                         \
      acc[KX + 1][KY + 1][c] += wv.w * hv[c];                         \
    } }

  #pragma unroll 4
  for (int e = 0; e < e1; ++e) EDGE_BODY(e, 0, 0)    // quad0: kx0=0, ky0=0
  #pragma unroll 4
  for (int e = e1; e < e2; ++e) EDGE_BODY(e, 1, 0)   // quad1: kx0=1, ky0=0
  #pragma unroll 4
  for (int e = e2; e < e3; ++e) EDGE_BODY(e, 0, 1)   // quad2: kx0=0, ky0=1
  #pragma unroll 4
  for (int e = e3; e < e4; ++e) EDGE_BODY(e, 1, 1)   // quad3: kx0=1, ky0=1
#undef EDGE_BODY

  // store: k = kx*3 + ky (reference reshape order); cols k*CIN + lane*CH
  _Float16* sr = sp + (size_t)row * KP + lane * CH;
  #pragma unroll
  for (int kx = 0; kx < 3; ++kx)
    #pragma unroll
    for (int ky = 0; ky < 3; ++ky) {
      int k = kx * 3 + ky;
      if (CH == 1) {
        sr[(size_t)k * CIN] = (_Float16)(acc[kx][ky][0] * di);
      } else {
        f16x2 p;
        p[0] = (_Float16)(acc[kx][ky][0] * di);
        p[1] = (_Float16)(acc[kx][ky][CH - 1] * di);
        *(f16x2*)&sr[(size_t)k * CIN] = p;
      }
    }
  // root column: h passthrough
  if (CH == 1) {
    sr[(size_t)9 * CIN] = hb[(size_t)n * 64];
  } else {
    *(unsigned*)&sr[(size_t)9 * CIN] = *(const unsigned*)&hb[(size_t)n * 128];
  }
}

// ---------------- dense GEMM: out[m,f] = relu( A[m,:]@Wt[f,:] + bias[f] ) ----------------
// A fp16 [16384][KP], Wt fp16 [64][KP]. M-tile 64 (grid 256), 256 thr = 4 waves,
// wave owns 16 rows x 64 cols, 16x16x32 f16 MFMA. Double-buffered LDS with
// issue-early/write-late staging (T14). Epilogue: fp16 h-out and/or fused
// max-pool (atomicMax on uint bits, relu >= 0).
#define GBK  64
#define GLDK 72
__global__ __launch_bounds__(256) void gemm_s_kernel(
    const _Float16* __restrict__ A, const _Float16* __restrict__ Wt,
    const float* __restrict__ bias, _Float16* __restrict__ hout,
    unsigned int* __restrict__ gmax, int KP) {
  __shared__ __attribute__((aligned(16))) _Float16 As[2][64 * GLDK];
  __shared__ __attribute__((aligned(16))) _Float16 Ws[2][64 * GLDK];
  int bm = blockIdx.x << 6;
  int tid = threadIdx.x, wave = tid >> 6, lane = tid & 63;
  int lr = lane & 15, quad = lane >> 4;
  int srow = tid >> 3, sck = (tid & 7) * 8;       // staging: rows srow, srow+32
  const size_t aoff = (size_t)(bm + srow) * KP + sck;
  const size_t woff = (size_t)srow * KP + sck;

  f32x4 acc[4] = {};
  // stage step 0 directly
  {
    *(float4*)&As[0][srow * GLDK + sck]        = *(const float4*)&A[aoff];
    *(float4*)&As[0][(srow + 32) * GLDK + sck] = *(const float4*)&A[aoff + (size_t)32 * KP];
    *(float4*)&Ws[0][srow * GLDK + sck]        = *(const float4*)&Wt[woff];
    *(float4*)&Ws[0][(srow + 32) * GLDK + sck] = *(const float4*)&Wt[woff + (size_t)32 * KP];
  }
  int S = KP / GBK, cur = 0;
  float4 pa0, pa1, pw0, pw1;
  for (int s = 0; s < S; ++s) {
    if (s + 1 < S) {                 // issue next tile's loads (no wait)
      int k0 = (s + 1) * GBK;
      pa0 = *(const float4*)&A[aoff + k0];
      pa1 = *(const float4*)&A[aoff + (size_t)32 * KP + k0];
      pw0 = *(const float4*)&Wt[woff + k0];
      pw1 = *(const float4*)&Wt[woff + (size_t)32 * KP + k0];
    }
    __syncthreads();                 // buf[cur] ready for all waves
    #pragma unroll
    for (int kk = 0; kk < GBK; kk += 32) {
      f16x8 af = *(const f16x8*)&As[cur][(16 * wave + lr) * GLDK + kk + quad * 8];
      #pragma unroll
      for (int j = 0; j < 4; ++j) {
        f16x8 bf = *(const f16x8*)&Ws[cur][(16 * j + lr) * GLDK + kk + quad * 8];
        acc[j] = __builtin_amdgcn_mfma_f32_16x16x32_f16(af, bf, acc[j], 0, 0, 0);
      }
    }
    if (s + 1 < S) {                 // write-late into the other buffer
      int nb = cur ^ 1;
      *(float4*)&As[nb][srow * GLDK + sck]        = pa0;
      *(float4*)&As[nb][(srow + 32) * GLDK + sck] = pa1;
      *(float4*)&Ws[nb][srow * GLDK + sck]        = pw0;
      *(float4*)&Ws[nb][(srow + 32) * GLDK + sck] = pw1;
    }
    cur ^= 1;
  }
  // epilogue: C layout col = lane&15, row = quad*4 + r (verified)
  int b = bm >> 9;
  #pragma unroll
  for (int j = 0; j < 4; ++j) {
    int f = 16 * j + lr;
    float bs = bias[f];
    float vmax = 0.0f;
    #pragma unroll
    for (int r = 0; r < 4; ++r) {
      int m = bm + (wave << 4) + (quad << 2) + r;
      float v = fmaxf(acc[j][r] + bs, 0.0f);
      if (hout) hout[(size_t)m * F_ + f] = (_Float16)v;
      vmax = fmaxf(vmax, v);
    }
    if (gmax) atomicMax(&gmax[(b << 6) + f], __float_as_uint(vmax));
  }
}

// ---------------- FC from pooled features ----------------
__global__ __launch_bounds__(64) void fc_kernel(
    const float* __restrict__ g, const float* __restrict__ fcw,
    const float* __restrict__ fcb, float* __restrict__ out) {
  int b = blockIdx.x;
  int f = threadIdx.x;
  __shared__ float gs[64];
  gs[f] = g[b * F_ + f];
  __syncthreads();
  if (f < 10) {
    float s = fcb[f];
    #pragma unroll
    for (int c = 0; c < 64; ++c) s += gs[c] * fcw[c * 10 + f];
    out[b * 10 + f] = s;
  }
}

extern "C" void kernel_launch(void* const* d_in, const int* in_sizes, int n_in,
                              void* d_out, int out_size, void* d_ws, size_t ws_size,
                              hipStream_t stream) {
  const float* x     = (const float*)d_in[0];
  const float* coord = (const float*)d_in[1];
  const float* adj   = (const float*)d_in[2];
  const float* w0    = (const float*)d_in[3];
  const float* root0 = (const float*)d_in[4];
  const float* b0    = (const float*)d_in[5];
  const float* w1    = (const float*)d_in[6];
  const float* root1 = (const float*)d_in[7];
  const float* b1    = (const float*)d_in[8];
  const float* w2    = (const float*)d_in[9];
  const float* root2 = (const float*)d_in[10];
  const float* b2    = (const float*)d_in[11];
  const float* fcw   = (const float*)d_in[12];
  const float* fcb   = (const float*)d_in[13];
  float* out = (float*)d_out;

  char* ws = (char*)d_ws;
  size_t off = 0;
  auto alloc = [&](size_t bytes) {
    void* p = ws + off;
    off = (off + bytes + 255) & ~(size_t)255;
    return p;
  };
  const int R = B_ * N_;  // 16384
  int*    edge_m  = (int*)   alloc((size_t)R * CAP * 4);
  float4* edge_w  = (float4*)alloc((size_t)R * CAP * 16);
  int4*   cnt4    = (int4*)  alloc((size_t)R * 16);
  float*  deginv  = (float*) alloc((size_t)R * 4);
  _Float16* hx    = (_Float16*)alloc((size_t)R * 128 * 2);   // fp16 x
  _Float16* wt0   = (_Float16*)alloc((size_t)64 * 1280 * 2);
  _Float16* wt1   = (_Float16*)alloc((size_t)64 * 640 * 2);
  _Float16* wt2   = (_Float16*)alloc((size_t)64 * 640 * 2);
  _Float16* sp    = (_Float16*)alloc((size_t)R * 1280 * 2);  // s (max K)
  _Float16* hA    = (_Float16*)alloc((size_t)R * 64 * 2);
  _Float16* hB    = (_Float16*)alloc((size_t)R * 64 * 2);
  unsigned int* gmax = (unsigned int*)alloc((size_t)B_ * F_ * 4);

  preprocess_kernel<<<R / 8, 512, 0, stream>>>(
      adj, coord, edge_m, edge_w, cnt4, deginv, gmax,
      x, hx, w0, root0, w1, root1, w2, root2, wt0, wt1, wt2);

  // layer 0: CIN=128, K = 1280
  gather_kernel<2><<<R / 4, 256, 0, stream>>>(hx, edge_m, edge_w, cnt4, deginv, sp);
  gemm_s_kernel<<<R / 64, 256, 0, stream>>>(sp, wt0, b0, hA, nullptr, 1280);

  // layer 1: CIN=64, K = 640
  gather_kernel<1><<<R / 4, 256, 0, stream>>>(hA, edge_m, edge_w, cnt4, deginv, sp);
  gemm_s_kernel<<<R / 64, 256, 0, stream>>>(sp, wt1, b1, hB, nullptr, 640);

  // layer 2: CIN=64, K = 640 — fused max-pool
  gather_kernel<1><<<R / 4, 256, 0, stream>>>(hB, edge_m, edge_w, cnt4, deginv, sp);
  gemm_s_kernel<<<R / 64, 256, 0, stream>>>(sp, wt2, b2, nullptr, gmax, 640);

  fc_kernel<<<B_, 64, 0, stream>>>((const float*)gmax, fcw, fcb, out);
}

// Round 20
// 206.263 us; speedup vs baseline: 1.4135x; 1.0357x over previous
//
#include <hip/hip_runtime.h>

// SplineCNN on MI355X — aggregate-before-GEMM, L2-direct gather (R16 base).
//
// Math order: s[n, k*CIN+c] = deginv * sum_{m in N(n)} basis_k(n,m) * h[m,c],
// root column appended -> one dense GEMM per layer:
//   out = relu( [s | h] @ [w; root] + bias ),  K = 10*CIN, N = 64.
// Measured best 213.6us (R19). Design ledger:
//  - gather: lean body, VGPR<=64 via launch_bounds(256,8) -> 8 waves/SIMD
//    (R13); precomputed tap weights in edge_w (R14). Deeper pipelines/unrolls
//    spill or halve occupancy (R8/R11/R18); slot-parallel (R12), fusion
//    (R7/R17), quadrant-per-wave (R10) all falsified.
//  - preprocess: barrier-free wave-per-row, two ballot passes, no LDS (R16);
//    merged with x->fp16 convert + weight pack + gmax zero.
//  - THIS ROUND: GEMM M-tile 64 -> 32 (grid 256 -> 512 = 2 blocks/CU). At
//    1 block/CU every K-step's barrier + ~900cy HBM A-load latency was fully
//    exposed; 2 resident blocks interleave compute with each other's loads.
//    Wave owns a 16-col slice of all 32 rows (2 MFMA/K-chunk); LDS 27.6KB;
//    3 float4 staging loads/thread/step. Same K-order -> bit-identical.
//  - XCD swizzle on gather: batch b's blocks on XCD b>>2 (h L2-resident).
// All tensors fp16 (fp32 accumulate in gather + MFMA); layer-2 GEMM epilogue
// fuses global max-pool via uint-bitcast atomicMax (relu >= 0).

#define B_   32
#define N_   512
#define F_   64
#define CAP  128          // max neighbors per node (mean ~31; P(>128) ~ 18 sigma)

typedef float f32x4 __attribute__((ext_vector_type(4)));
typedef _Float16 f16x8 __attribute__((ext_vector_type(8)));
typedef _Float16 f16x2 __attribute__((ext_vector_type(2)));

// ---------------- preprocess: wave-per-row, barrier-free ----------------
// edge_m[row*CAP+i] = neighbor index m; edge_w[row*CAP+i] = {w00,w01,w10,w11}
// (bilinear tap weights, f32, precomputed). Sorted by quad = kx0 + 2*ky0,
// ascending m within each quad. cnt4[row] = clamped cumulative quad counts;
// deginv = 1/clip(deg,1). Grid 2048 x 512: wave w of block i handles row
// i*8+w. Also merged prep (x fp32->fp16 + pack [w;root] -> Wt) + gmax zero.
__global__ __launch_bounds__(512, 8) void preprocess_kernel(
    const float* __restrict__ adj, const float* __restrict__ coord,
    int* __restrict__ edge_m, float4* __restrict__ edge_w,
    int4* __restrict__ cnt4,
    float* __restrict__ deginv, unsigned int* __restrict__ gmax,
    const float* __restrict__ x, _Float16* __restrict__ hx,
    const float* __restrict__ w0, const float* __restrict__ root0,
    const float* __restrict__ w1, const float* __restrict__ root1,
    const float* __restrict__ w2, const float* __restrict__ root2,
    _Float16* __restrict__ wt0, _Float16* __restrict__ wt1,
    _Float16* __restrict__ wt2) {
  int tid = threadIdx.x, wave = tid >> 6, lane = tid & 63;
  if (tid == 0) gmax[blockIdx.x] = 0u;   // grid 2048 == B_*F_

  // ---- merged prep: idx space [0, R*32) convx; then packw for 3 layers ----
  {
    int idx = blockIdx.x * 512 + tid;    // covers 1,048,576 >= 688,128
    const int CX = B_ * N_ * 32;
    const int S0 = 64 * 1280, S1 = 64 * 640;
    if (idx < CX) {
      float4 v = ((const float4*)x)[idx];
      f16x2 p0, p1;
      p0[0] = (_Float16)v.x; p0[1] = (_Float16)v.y;
      p1[0] = (_Float16)v.z; p1[1] = (_Float16)v.w;
      uint2 u;
      u.x = __builtin_bit_cast(unsigned, p0);
      u.y = __builtin_bit_cast(unsigned, p1);
      ((uint2*)hx)[idx] = u;
    } else if (idx < CX + S0 + 2 * S1) {
      int r = idx - CX;
      const float *w, *root; _Float16* wt; int KP, CIN;
      if (r < S0)           { w = w0; root = root0; wt = wt0; KP = 1280; CIN = 128; }
      else if (r < S0 + S1) { w = w1; root = root1; wt = wt1; KP = 640;  CIN = 64;  r -= S0; }
      else                  { w = w2; root = root2; wt = wt2; KP = 640;  CIN = 64;  r -= S0 + S1; }
      int f = r / KP, k = r - f * KP;
      int ks = k / CIN, c = k - ks * CIN;
      float v = (ks < 9) ? w[((size_t)ks * CIN + c) * F_ + f]
                         : root[(size_t)c * F_ + f];
      wt[(size_t)f * KP + k] = (_Float16)v;
    }
  }

  int row = blockIdx.x * 8 + wave;       // one row per wave
  int b = row >> 9;
  float cxn = coord[(size_t)row * 2 + 0];
  float cyn = coord[(size_t)row * 2 + 1];

  // ---- pass 1: load + classify 8 chunks of 64; wave-uniform quad totals ----
  int   pq[8];                  // quad (0..3) or -1 if no edge
  float pfx[8], pfy[8];
  int q0 = 0, q1 = 0, q2 = 0, q3 = 0;
  #pragma unroll
  for (int c = 0; c < 8; ++c) {
    int m = c * 64 + lane;
    float a = adj[(size_t)row * N_ + m];
    bool flag = (a != 0.0f);
    float cxm = coord[(size_t)(b * N_ + m) * 2 + 0];
    float cym = coord[(size_t)(b * N_ + m) * 2 + 1];
    float vx = cxm - cxn + 1.0f;         // = u*2 (K-1 = 2, u in [0,1])
    float vy = cym - cyn + 1.0f;
    float i0x = fminf(fmaxf(floorf(vx), 0.0f), 1.0f);
    float i0y = fminf(fmaxf(floorf(vy), 0.0f), 1.0f);
    pfx[c] = vx - i0x;
    pfy[c] = vy - i0y;
    int quad = (int)i0x + 2 * (int)i0y;  // 0..3
    pq[c] = flag ? quad : -1;
    q0 += __popcll(__ballot(flag && quad == 0));
    q1 += __popcll(__ballot(flag && quad == 1));
    q2 += __popcll(__ballot(flag && quad == 2));
    q3 += __popcll(__ballot(flag && quad == 3));
  }
  int qt0 = q0, qt1 = q0 + q1, qt2 = qt1 + q2, qt3 = qt2 + q3;

  // ---- pass 2: running per-quad offsets -> quad-sorted edge writes ----
  int ro0 = 0, ro1 = qt0, ro2 = qt1, ro3 = qt2;   // quad base offsets
  #pragma unroll
  for (int c = 0; c < 8; ++c) {
    unsigned long long b0 = __ballot(pq[c] == 0);
    unsigned long long b1 = __ballot(pq[c] == 1);
    unsigned long long b2 = __ballot(pq[c] == 2);
    unsigned long long b3 = __ballot(pq[c] == 3);
    int q = pq[c];
    if (q >= 0) {
      unsigned long long myb = (q == 0) ? b0 : (q == 1) ? b1 : (q == 2) ? b2 : b3;
      int base = (q == 0) ? ro0 : (q == 1) ? ro1 : (q == 2) ? ro2 : ro3;
      int off = base + __popcll(myb & ((1ULL << lane) - 1ULL));
      if (off < CAP) {
        float fx = pfx[c], fy = pfy[c];
        float gx = 1.0f - fx, gy = 1.0f - fy;
        edge_m[(size_t)row * CAP + off] = c * 64 + lane;
        edge_w[(size_t)row * CAP + off] =
            make_float4(gx * gy, gx * fy, fx * gy, fx * fy);
      }
    }
    ro0 += __popcll(b0); ro1 += __popcll(b1);
    ro2 += __popcll(b2); ro3 += __popcll(b3);
  }
  if (lane == 0) {
    int C0 = min(qt0, CAP), C1 = min(qt1, CAP);
    int C2 = min(qt2, CAP), C3c = min(qt3, CAP);
    cnt4[row] = make_int4(C0, C1 - C0, C2 - C1, C3c - C2);
    deginv[row] = 1.0f / (float)(qt3 > 0 ? qt3 : 1);
  }
}

// ---------------- gather: s[row, k*CIN + c] = deginv * sum basis_k * h[m,c] ----------------
// 256 threads = 4 waves, ONE ROW PER WAVE; grid 4096, XCD-swizzled so batch b's
// blocks share an XCD (h slice <=512KB L2-resident). Wave stages its row's edge
// list (m + precomputed weights) to LDS, then hot loop: 2 broadcast LDS reads
// + contiguous 128/256B global h gather (L2 hit) + 2 cvt + 4*CH FMAs, unroll 4.
// __launch_bounds__(256,8) pins VGPR <= 64 (8 waves/SIMD; lean body fits).
// Quadrant runs give static accumulator targets. CH = CIN/64 channels/lane.
template<int CH>
__global__ __launch_bounds__(256, 8) void gather_kernel(
    const _Float16* __restrict__ hsrc,   // [16384][CIN] fp16
    const int* __restrict__ edge_m, const float4* __restrict__ edge_w,
    const int4* __restrict__ cnt4,
    const float* __restrict__ deginv,
    _Float16* __restrict__ sp) {         // [16384][KP]
  const int CIN = 64 * CH, KP = 10 * CIN;
  __shared__ float4 eshw[4][CAP];
  __shared__ int eshm[4][CAP];
  int wave = threadIdx.x >> 6, lane = threadIdx.x & 63;
  int xcd = blockIdx.x & 7;
  int j = blockIdx.x >> 3;
  int b = xcd * 4 + (j >> 7);
  int n = ((j & 127) << 2) + wave;          // row within batch
  int row = (b << 9) + n;
  int4 c4 = cnt4[row];
  int e1 = c4.x, e2 = e1 + c4.y, e3 = e2 + c4.z, e4 = e3 + c4.w;
  size_t ebase = (size_t)row * CAP;
  for (int i = lane; i < e4; i += 64) {     // wave-private region, no barrier
    eshw[wave][i] = edge_w[ebase + i];
    eshm[wave][i] = edge_m[ebase + i];
  }
  float di = deginv[row];
  const _Float16* hb = hsrc + (size_t)b * N_ * CIN + lane * CH;

  float acc[3][3][CH];
  #pragma unroll
  for (int kx = 0; kx < 3; ++kx)
    #pragma unroll
    for (int ky = 0; ky < 3; ++ky)
      #pragma unroll
      for (int c = 0; c < CH; ++c) acc[kx][ky][c] = 0.0f;

#define EDGE_BODY(E, KX, KY) {                                        \
    int m = eshm[wave][E];                                            \
    float4 wv = eshw[wave][E];                                        \
    float hv[CH];                                                     \
    if (CH == 1) {                                                    \
      hv[0] = (float)hb[(size_t)m * 64];                              \
    } else {                                                          \
      unsigned u = *(const unsigned*)&hb[(size_t)m * 128];            \
      f16x2 hp = __builtin_bit_cast(f16x2, u);                        \
      hv[0] = (float)hp[0]; hv[CH - 1] = (float)hp[1];                \
    }                                                                 \
    _Pragma("unroll")                                                 \
    for (int c = 0; c < CH; ++c) {                                    \
      acc[KX][KY][c]         += wv.x * hv[c];                         \
      acc[KX][KY + 1][c]     += wv.y * hv[c];                         \
      acc[KX + 1][KY][c]     += wv.z * hv[c];                         \
      acc[KX + 1][KY + 1][c] += wv.w * hv[c];                         \
    } }

  #pragma unroll 4
  for (int e = 0; e < e1; ++e) EDGE_BODY(e, 0, 0)    // quad0: kx0=0, ky0=0
  #pragma unroll 4
  for (int e = e1; e < e2; ++e) EDGE_BODY(e, 1, 0)   // quad1: kx0=1, ky0=0
  #pragma unroll 4
  for (int e = e2; e < e3; ++e) EDGE_BODY(e, 0, 1)   // quad2: kx0=0, ky0=1
  #pragma unroll 4
  for (int e = e3; e < e4; ++e) EDGE_BODY(e, 1, 1)   // quad3: kx0=1, ky0=1
#undef EDGE_BODY

  // store: k = kx*3 + ky (reference reshape order); cols k*CIN + lane*CH
  _Float16* sr = sp + (size_t)row * KP + lane * CH;
  #pragma unroll
  for (int kx = 0; kx < 3; ++kx)
    #pragma unroll
    for (int ky = 0; ky < 3; ++ky) {
      int k = kx * 3 + ky;
      if (CH == 1) {
        sr[(size_t)k * CIN] = (_Float16)(acc[kx][ky][0] * di);
      } else {
        f16x2 p;
        p[0] = (_Float16)(acc[kx][ky][0] * di);
        p[1] = (_Float16)(acc[kx][ky][CH - 1] * di);
        *(f16x2*)&sr[(size_t)k * CIN] = p;
      }
    }
  // root column: h passthrough
  if (CH == 1) {
    sr[(size_t)9 * CIN] = hb[(size_t)n * 64];
  } else {
    *(unsigned*)&sr[(size_t)9 * CIN] = *(const unsigned*)&hb[(size_t)n * 128];
  }
}

// ---------------- dense GEMM: out[m,f] = relu( A[m,:]@Wt[f,:] + bias[f] ) ----------------
// A fp16 [16384][KP], Wt fp16 [64][KP]. M-tile 32 (grid 512 = 2 blocks/CU),
// 256 thr = 4 waves; wave owns a 16-COL slice of all 32 rows (2 MFMA/K-chunk).
// Double-buffered LDS (27.6KB) with issue-early/write-late staging (T14);
// 3 float4 staging loads/thread/step. Epilogue: fp16 h-out and/or fused
// max-pool (atomicMax on uint bits, relu >= 0).
#define GBK  64
#define GLDK 72
__global__ __launch_bounds__(256) void gemm_s_kernel(
    const _Float16* __restrict__ A, const _Float16* __restrict__ Wt,
    const float* __restrict__ bias, _Float16* __restrict__ hout,
    unsigned int* __restrict__ gmax, int KP) {
  __shared__ __attribute__((aligned(16))) _Float16 As[2][32 * GLDK];
  __shared__ __attribute__((aligned(16))) _Float16 Ws[2][64 * GLDK];
  int bm = blockIdx.x << 5;
  int tid = threadIdx.x, wave = tid >> 6, lane = tid & 63;
  int lr = lane & 15, quad = lane >> 4;
  int srow = tid >> 3, sck = (tid & 7) * 8;   // A: row srow; W: rows srow, srow+32
  const size_t aoff = (size_t)(bm + srow) * KP + sck;
  const size_t woff = (size_t)srow * KP + sck;

  f32x4 acc0 = {0.f, 0.f, 0.f, 0.f}, acc1 = {0.f, 0.f, 0.f, 0.f};
  // stage step 0 directly
  {
    *(float4*)&As[0][srow * GLDK + sck]        = *(const float4*)&A[aoff];
    *(float4*)&Ws[0][srow * GLDK + sck]        = *(const float4*)&Wt[woff];
    *(float4*)&Ws[0][(srow + 32) * GLDK + sck] = *(const float4*)&Wt[woff + (size_t)32 * KP];
  }
  int S = KP / GBK, cur = 0;
  float4 pa0, pw0, pw1;
  for (int s = 0; s < S; ++s) {
    if (s + 1 < S) {                 // issue next tile's loads (no wait)
      int k0 = (s + 1) * GBK;
      pa0 = *(const float4*)&A[aoff + k0];
      pw0 = *(const float4*)&Wt[woff + k0];
      pw1 = *(const float4*)&Wt[woff + (size_t)32 * KP + k0];
    }
    __syncthreads();                 // buf[cur] ready for all waves
    #pragma unroll
    for (int kk = 0; kk < GBK; kk += 32) {
      f16x8 bf  = *(const f16x8*)&Ws[cur][((wave << 4) + lr) * GLDK + kk + quad * 8];
      f16x8 af0 = *(const f16x8*)&As[cur][lr * GLDK + kk + quad * 8];
      f16x8 af1 = *(const f16x8*)&As[cur][(16 + lr) * GLDK + kk + quad * 8];
      acc0 = __builtin_amdgcn_mfma_f32_16x16x32_f16(af0, bf, acc0, 0, 0, 0);
      acc1 = __builtin_amdgcn_mfma_f32_16x16x32_f16(af1, bf, acc1, 0, 0, 0);
    }
    if (s + 1 < S) {                 // write-late into the other buffer
      int nb = cur ^ 1;
      *(float4*)&As[nb][srow * GLDK + sck]        = pa0;
      *(float4*)&Ws[nb][srow * GLDK + sck]        = pw0;
      *(float4*)&Ws[nb][(srow + 32) * GLDK + sck] = pw1;
    }
    cur ^= 1;
  }
  // epilogue: C layout col = lane&15 (here: W col f), row = quad*4 + r
  int b = bm >> 9;
  int f = (wave << 4) + lr;
  float bs = bias[f];
  float vmax = 0.0f;
  #pragma unroll
  for (int r = 0; r < 4; ++r) {
    int m0 = bm + (quad << 2) + r;          // rows 0-15 tile
    float v0 = fmaxf(acc0[r] + bs, 0.0f);
    if (hout) hout[(size_t)m0 * F_ + f] = (_Float16)v0;
    vmax = fmaxf(vmax, v0);
    int m1 = bm + 16 + (quad << 2) + r;     // rows 16-31 tile
    float v1 = fmaxf(acc1[r] + bs, 0.0f);
    if (hout) hout[(size_t)m1 * F_ + f] = (_Float16)v1;
    vmax = fmaxf(vmax, v1);
  }
  if (gmax) atomicMax(&gmax[(b << 6) + f], __float_as_uint(vmax));
}

// ---------------- FC from pooled features ----------------
__global__ __launch_bounds__(64) void fc_kernel(
    const float* __restrict__ g, const float* __restrict__ fcw,
    const float* __restrict__ fcb, float* __restrict__ out) {
  int b = blockIdx.x;
  int f = threadIdx.x;
  __shared__ float gs[64];
  gs[f] = g[b * F_ + f];
  __syncthreads();
  if (f < 10) {
    float s = fcb[f];
    #pragma unroll
    for (int c = 0; c < 64; ++c) s += gs[c] * fcw[c * 10 + f];
    out[b * 10 + f] = s;
  }
}

extern "C" void kernel_launch(void* const* d_in, const int* in_sizes, int n_in,
                              void* d_out, int out_size, void* d_ws, size_t ws_size,
                              hipStream_t stream) {
  const float* x     = (const float*)d_in[0];
  const float* coord = (const float*)d_in[1];
  const float* adj   = (const float*)d_in[2];
  const float* w0    = (const float*)d_in[3];
  const float* root0 = (const float*)d_in[4];
  const float* b0    = (const float*)d_in[5];
  const float* w1    = (const float*)d_in[6];
  const float* root1 = (const float*)d_in[7];
  const float* b1    = (const float*)d_in[8];
  const float* w2    = (const float*)d_in[9];
  const float* root2 = (const float*)d_in[10];
  const float* b2    = (const float*)d_in[11];
  const float* fcw   = (const float*)d_in[12];
  const float* fcb   = (const float*)d_in[13];
  float* out = (float*)d_out;

  char* ws = (char*)d_ws;
  size_t off = 0;
  auto alloc = [&](size_t bytes) {
    void* p = ws + off;
    off = (off + bytes + 255) & ~(size_t)255;
    return p;
  };
  const int R = B_ * N_;  // 16384
  int*    edge_m  = (int*)   alloc((size_t)R * CAP * 4);
  float4* edge_w  = (float4*)alloc((size_t)R * CAP * 16);
  int4*   cnt4    = (int4*)  alloc((size_t)R * 16);
  float*  deginv  = (float*) alloc((size_t)R * 4);
  _Float16* hx    = (_Float16*)alloc((size_t)R * 128 * 2);   // fp16 x
  _Float16* wt0   = (_Float16*)alloc((size_t)64 * 1280 * 2);
  _Float16* wt1   = (_Float16*)alloc((size_t)64 * 640 * 2);
  _Float16* wt2   = (_Float16*)alloc((size_t)64 * 640 * 2);
  _Float16* sp    = (_Float16*)alloc((size_t)R * 1280 * 2);  // s (max K)
  _Float16* hA    = (_Float16*)alloc((size_t)R * 64 * 2);
  _Float16* hB    = (_Float16*)alloc((size_t)R * 64 * 2);
  unsigned int* gmax = (unsigned int*)alloc((size_t)B_ * F_ * 4);

  preprocess_kernel<<<R / 8, 512, 0, stream>>>(
      adj, coord, edge_m, edge_w, cnt4, deginv, gmax,
      x, hx, w0, root0, w1, root1, w2, root2, wt0, wt1, wt2);

  // layer 0: CIN=128, K = 1280
  gather_kernel<2><<<R / 4, 256, 0, stream>>>(hx, edge_m, edge_w, cnt4, deginv, sp);
  gemm_s_kernel<<<R / 32, 256, 0, stream>>>(sp, wt0, b0, hA, nullptr, 1280);

  // layer 1: CIN=64, K = 640
  gather_kernel<1><<<R / 4, 256, 0, stream>>>(hA, edge_m, edge_w, cnt4, deginv, sp);
  gemm_s_kernel<<<R / 32, 256, 0, stream>>>(sp, wt1, b1, hB, nullptr, 640);

  // layer 2: CIN=64, K = 640 — fused max-pool
  gather_kernel<1><<<R / 4, 256, 0, stream>>>(hB, edge_m, edge_w, cnt4, deginv, sp);
  gemm_s_kernel<<<R / 32, 256, 0, stream>>>(sp, wt2, b2, nullptr, gmax, 640);

  fc_kernel<<<B_, 64, 0, stream>>>((const float*)gmax, fcw, fcb, out);
}